// Round 6
// baseline (2128.410 us; speedup 1.0000x reference)
//
#include <hip/hip_runtime.h>
#include <hip/hip_bf16.h>
#include <cstddef>

// ---------------------------------------------------------------------------
// UNet_config1 forward — MFMA implicit-GEMM, NHWC, fp16 storage / fp32 accum.
// R6: no persistent staging arrays (regs -> occupancy 3 blk/CU), explicit
// 1-tap A-frag prefetch, launch_bounds(256,3). LDS dbuf kept.
// ---------------------------------------------------------------------------

typedef _Float16 h16;
typedef __attribute__((ext_vector_type(8))) _Float16 h16x8;
typedef __attribute__((ext_vector_type(4))) float f32x4;
union F8 { uint4 u; h16x8 h; };

__device__ __forceinline__ float h2f(unsigned short s) {
    union { h16 h; unsigned short s; } c; c.s = s; return (float)c.h;
}
__device__ __forceinline__ unsigned short f2h(float f) {
    union { h16 h; unsigned short s; } c; c.h = (h16)f; return c.s;
}
__device__ __forceinline__ unsigned pack2(float a, float b) {
    return (unsigned)f2h(a) | ((unsigned)f2h(b) << 16);
}
__device__ __forceinline__ void up8(const uint4& v, float* f) {
    f[0]=h2f(v.x&0xffff); f[1]=h2f(v.x>>16);
    f[2]=h2f(v.y&0xffff); f[3]=h2f(v.y>>16);
    f[4]=h2f(v.z&0xffff); f[5]=h2f(v.z>>16);
    f[6]=h2f(v.w&0xffff); f[7]=h2f(v.w>>16);
}

// ---- weight pack: fp32 [O][I][KH][KW] -> fp16 [O][T][I] -------------------
__global__ void k_pack(const float* __restrict__ w, h16* __restrict__ pw,
                       int I, int T)
{
    int i = blockIdx.x * 64 + threadIdx.x;
    if (i >= I) return;
    int t = blockIdx.y, o = blockIdx.z;
    pw[((size_t)o * T + t) * I + i] = (h16)w[((size_t)o * I + i) * T + t];
}

// ---- implicit-GEMM conv: (16*MT) Cout x 256 px tile, 4 waves --------------
// src1: channels [0,C1n). If UPS, src1 is low-res (H1,W1) bilinearly
// upsampled x2 (align_corners) during staging; src2 = skip at (Hin,Win).
// Non-UPS: single source src1 at (H1,W1), C2n must be 0.
template<int KH, int KW, int PAD, bool UPS, int MT>
__global__ __launch_bounds__(256, 3) void k_conv_mfma(
    const h16* __restrict__ src1, int C1n, int H1, int W1,
    const h16* __restrict__ src2, int C2n,
    int Hin, int Win, int Ho, int Wo,
    const h16* __restrict__ PW, const float* __restrict__ bias,
    const float* __restrict__ pa, int aidx,
    h16* __restrict__ out, int Cout)
{
    constexpr int WINH = 8 + KH - 1, WINW = 32 + KW - 1;
    constexpr int NPIX = WINH * WINW;
    constexpr int NIT  = NPIX * 4;
    constexpr int MAXIT = (NIT + 255) / 256;
    constexpr int TAPS = KH * KW;
    __shared__ unsigned short lds[2][NPIX * 36];

    const int tid = threadIdx.x;
    const int lane = tid & 63, wv = tid >> 6;
    const int quad = lane >> 4, m16 = lane & 15;
    const int nCb = Cout / (16 * MT);
    const int b  = blockIdx.z / nCb, cb = blockIdx.z % nCb;
    const int x0 = blockIdx.x * 32, y0 = blockIdx.y * 8;
    const int Cin = C1n + C2n;
    const int co_base = cb * (16 * MT);
    const int srcH = UPS ? Hin : H1;       // full-res dims of the window
    const int srcW = UPS ? Win : W1;

    const float ry = UPS ? (float)(H1 - 1) / (float)(Hin - 1) : 0.f;
    const float rx = UPS ? (float)(W1 - 1) / (float)(Win - 1) : 0.f;
    const int W1C = UPS ? W1 * C1n : 0;

    // ---- accumulators & A-frag base pointers ----
    f32x4 acc[MT][4];
#pragma unroll
    for (int i = 0; i < MT; ++i)
#pragma unroll
        for (int j = 0; j < 4; ++j) acc[i][j] = (f32x4){0.f, 0.f, 0.f, 0.f};

    const uint4* pwb[MT];
#pragma unroll
    for (int mt = 0; mt < MT; ++mt)
        pwb[mt] = (const uint4*)(PW + (size_t)(co_base + mt * 16 + m16) * TAPS * Cin + quad * 8);

    // ---- staging (addresses recomputed per call; no persistent arrays) ----
    auto stage = [&](int c0, unsigned short* buf) {
#pragma unroll
        for (int it = 0; it < MAXIT; ++it) {
            int i = tid + it * 256;
            if (i >= NIT) continue;
            int q = i & 3, p = i >> 2;
            int wy = p / WINW, wx = p - wy * WINW;
            int yy = y0 - PAD + wy, xx = x0 - PAD + wx;
            int lo = p * 36 + q * 8;
            bool val = (unsigned)yy < (unsigned)srcH && (unsigned)xx < (unsigned)srcW;
            if (UPS && c0 < C1n) {
                uint2 lo8 = {0u, 0u}, hi8 = {0u, 0u};
                if (val) {
                    float ys = yy * ry, xs = xx * rx;
                    int yl0 = (int)ys, xl0 = (int)xs;
                    float fyf = ys - (float)yl0, fxf = xs - (float)xl0;
                    const h16* p00 = src1 + ((b * H1 + yl0) * W1 + xl0) * C1n + q * 8 + c0;
                    int oy = (yl0 < H1 - 1) ? W1C : 0;
                    int ox = (xl0 < W1 - 1) ? C1n : 0;
                    F8 v00, v01, v10, v11;
                    v00.u = *(const uint4*)(p00);
                    v01.u = *(const uint4*)(p00 + ox);
                    v10.u = *(const uint4*)(p00 + oy);
                    v11.u = *(const uint4*)(p00 + oy + ox);
                    h16 fy = (h16)fyf, fx = (h16)fxf;
                    h16x8 r0 = v00.h + (v10.h - v00.h) * fy;
                    h16x8 r1 = v01.h + (v11.h - v01.h) * fy;
                    F8 rr; rr.h = r0 + (r1 - r0) * fx;
                    lo8 = make_uint2(rr.u.x, rr.u.y);
                    hi8 = make_uint2(rr.u.z, rr.u.w);
                }
                *(uint2*)&buf[lo] = lo8;
                *(uint2*)&buf[lo + 4] = hi8;
            } else if (UPS) {
                uint4 v = {0u, 0u, 0u, 0u};
                if (val)
                    v = *(const uint4*)(src2 + ((b * Hin + yy) * Win + xx) * C2n + q * 8 + (c0 - C1n));
                *(uint2*)&buf[lo] = make_uint2(v.x, v.y);
                *(uint2*)&buf[lo + 4] = make_uint2(v.z, v.w);
            } else {
                uint4 v = {0u, 0u, 0u, 0u};
                if (val)
                    v = *(const uint4*)(src1 + ((b * H1 + yy) * W1 + xx) * C1n + q * 8 + c0);
                *(uint2*)&buf[lo] = make_uint2(v.x, v.y);
                *(uint2*)&buf[lo + 4] = make_uint2(v.z, v.w);
            }
        }
    };

    // ---- MFMA sweep with 1-tap-ahead A-frag prefetch ----
    auto sweep = [&](int c0, const unsigned short* buf) {
        F8 a_cur[MT], a_nxt[MT];
#pragma unroll
        for (int mt = 0; mt < MT; ++mt)
            a_cur[mt].u = pwb[mt][c0 >> 3];
#pragma unroll
        for (int ky = 0; ky < KH; ++ky) {
#pragma unroll
            for (int kx = 0; kx < KW; ++kx) {
                const int tap = ky * KW + kx;
                if (tap + 1 < TAPS) {
#pragma unroll
                    for (int mt = 0; mt < MT; ++mt)
                        a_nxt[mt].u = pwb[mt][((tap + 1) * Cin + c0) >> 3];
                }
#pragma unroll
                for (int nt = 0; nt < 4; ++nt) {
                    int rowl = (wv << 1) + (nt >> 1);
                    int col  = ((nt & 1) << 4) + m16;
                    int li = ((rowl + ky) * WINW + col + kx) * 36 + quad * 8;
                    F8 bf;
                    ((uint2*)&bf)[0] = *(const uint2*)&buf[li];
                    ((uint2*)&bf)[1] = *(const uint2*)&buf[li + 4];
#pragma unroll
                    for (int mt = 0; mt < MT; ++mt)
                        acc[mt][nt] = __builtin_amdgcn_mfma_f32_16x16x32_f16(
                            a_cur[mt].h, bf.h, acc[mt][nt], 0, 0, 0);
                }
#pragma unroll
                for (int mt = 0; mt < MT; ++mt) a_cur[mt] = a_nxt[mt];
            }
        }
    };

    // ---- double-buffered K-loop: one barrier per chunk ----
    const int nch = Cin >> 5;
    stage(0, lds[0]);
    __syncthreads();
    for (int ci = 0; ci < nch; ++ci) {
        int p = ci & 1;
        if (ci + 1 < nch) stage((ci + 1) << 5, lds[p ^ 1]);
        sweep(ci << 5, lds[p]);
        __syncthreads();
    }

    // ---- epilogue: bias + PReLU, NHWC store ----
    const float alpha = pa[aidx];
#pragma unroll
    for (int mt = 0; mt < MT; ++mt) {
        int co = co_base + mt * 16 + quad * 4;
        float4 bi = *(const float4*)(bias + co);
#pragma unroll
        for (int nt = 0; nt < 4; ++nt) {
            int y = y0 + (wv << 1) + (nt >> 1);
            int x = x0 + ((nt & 1) << 4) + m16;
            float v0 = acc[mt][nt][0] + bi.x;
            float v1 = acc[mt][nt][1] + bi.y;
            float v2 = acc[mt][nt][2] + bi.z;
            float v3 = acc[mt][nt][3] + bi.w;
            v0 = v0 >= 0.f ? v0 : alpha * v0;
            v1 = v1 >= 0.f ? v1 : alpha * v1;
            v2 = v2 >= 0.f ? v2 : alpha * v2;
            v3 = v3 >= 0.f ? v3 : alpha * v3;
            uint2 r; r.x = pack2(v0, v1); r.y = pack2(v2, v3);
            *(uint2*)(out + ((size_t)((b * Ho + y) * Wo + x)) * Cout + co) = r;
        }
    }
}

// ---- dynamic per-sample conv 8x8 pad3 + PReLU[0], NHWC out ----------------
__global__ __launch_bounds__(256) void k_dynconv(
    const float* __restrict__ x,   // [8,256,256] fp32
    const float* __restrict__ w,   // [8,32,8,8] fp32
    const float* __restrict__ pa,
    h16* __restrict__ out)         // [8,255,255,32] NHWC
{
    __shared__ float wl[2048];     // [tap][co]
    int b = blockIdx.y;
    for (int j = threadIdx.x; j < 2048; j += 256) {
        int t = j >> 5, co = j & 31;
        wl[j] = w[((size_t)(b * 32 + co)) * 64 + t];
    }
    __syncthreads();
    int idx = blockIdx.x * 256 + threadIdx.x;
    if (idx >= 65025) return;
    int py = idx / 255, px = idx - py * 255;
    float acc[32];
#pragma unroll
    for (int c = 0; c < 32; ++c) acc[c] = 0.f;
    const float* xp = x + (size_t)b * 65536;
#pragma unroll
    for (int ky = 0; ky < 8; ++ky) {
        int iy = py + ky - 3;
        if ((unsigned)iy >= 256u) continue;
        const float* row = xp + iy * 256;
#pragma unroll
        for (int kx = 0; kx < 8; ++kx) {
            int ix = px + kx - 3;
            if ((unsigned)ix >= 256u) continue;
            float v = row[ix];
            const float4* wr = (const float4*)&wl[(ky * 8 + kx) * 32];
#pragma unroll
            for (int cg = 0; cg < 8; ++cg) {
                float4 wv = wr[cg];
                acc[cg*4+0] += v * wv.x; acc[cg*4+1] += v * wv.y;
                acc[cg*4+2] += v * wv.z; acc[cg*4+3] += v * wv.w;
            }
        }
    }
    float a = pa[0];
    h16* op = out + ((size_t)(b * 65025 + idx)) * 32;
#pragma unroll
    for (int cg = 0; cg < 4; ++cg) {
        float v[8];
#pragma unroll
        for (int k = 0; k < 8; ++k) {
            float t = acc[cg * 8 + k];
            v[k] = t >= 0.f ? t : a * t;
        }
        uint4 r;
        r.x = pack2(v[0], v[1]); r.y = pack2(v[2], v[3]);
        r.z = pack2(v[4], v[5]); r.w = pack2(v[6], v[7]);
        *(uint4*)(op + cg * 8) = r;
    }
}

// ---- maxpool 2x2, NHWC, vector 8ch ----------------------------------------
__global__ __launch_bounds__(256) void k_pool(
    const h16* __restrict__ in, h16* __restrict__ out,
    int Hin, int Win, int C, int lc8, int lwo, int count)
{
    int idx = blockIdx.x * 256 + threadIdx.x;
    if (idx >= count) return;
    int b = blockIdx.y;
    int c8 = idx & ((1 << lc8) - 1);
    int t  = idx >> lc8;
    int ox = t & ((1 << lwo) - 1);
    int oy = t >> lwo;
    const h16* p = in + ((size_t)((b * Hin + oy * 2) * Win + ox * 2)) * C + c8 * 8;
    uint4 v00 = *(const uint4*)p;
    uint4 v01 = *(const uint4*)(p + C);
    uint4 v10 = *(const uint4*)(p + (size_t)Win * C);
    uint4 v11 = *(const uint4*)(p + (size_t)Win * C + C);
    float a[8], bb[8], c[8], d[8];
    up8(v00, a); up8(v01, bb); up8(v10, c); up8(v11, d);
    uint4 r;
    float m[8];
#pragma unroll
    for (int k = 0; k < 8; ++k) m[k] = fmaxf(fmaxf(a[k], bb[k]), fmaxf(c[k], d[k]));
    r.x = pack2(m[0], m[1]); r.y = pack2(m[2], m[3]);
    r.z = pack2(m[4], m[5]); r.w = pack2(m[6], m[7]);
    int Wo = 1 << lwo;
    *(uint4*)(out + ((size_t)((b * (Hin >> 1) + oy) * Wo + ox)) * C + c8 * 8) = r;
}

// ---- BatchNorm (training stats), NHWC -------------------------------------
__global__ __launch_bounds__(256) void k_bnstats(
    const h16* __restrict__ x, int C, int N, float* __restrict__ sums)
{
    __shared__ float ls[1024];
    for (int j = threadIdx.x; j < 2 * C; j += 256) ls[j] = 0.f;
    __syncthreads();
    int start = blockIdx.x * 256 + threadIdx.x;
    int stride = gridDim.x * 256;
    int c = start & (C - 1);
    float s = 0.f, q = 0.f;
    for (int i = start; i < N; i += stride) {
        float v = h2f(((const unsigned short*)x)[i]);
        s += v; q += v * v;
    }
    atomicAdd(&ls[c], s);
    atomicAdd(&ls[C + c], q);
    __syncthreads();
    for (int j = threadIdx.x; j < 2 * C; j += 256) atomicAdd(&sums[j], ls[j]);
}

__global__ void k_bnfin(
    const float* __restrict__ sums, const float* __restrict__ g,
    const float* __restrict__ bta, int C, float invN, float* __restrict__ sc)
{
    int c = threadIdx.x;
    if (c >= C) return;
    float mean = sums[c] * invN;
    float var  = sums[C + c] * invN - mean * mean;
    float s    = g[c] / sqrtf(var + 1e-5f);
    sc[c]      = s;
    sc[C + c]  = bta[c] - mean * s;
}

__global__ __launch_bounds__(256) void k_bnapply(
    h16* __restrict__ x, int C, int N8, const float* __restrict__ sc)
{
    __shared__ float ls[1024];
    for (int j = threadIdx.x; j < 2 * C; j += 256) ls[j] = sc[j];
    __syncthreads();
    int idx = blockIdx.x * 256 + threadIdx.x;
    if (idx >= N8) return;
    int cb = (idx << 3) & (C - 1);
    h16* p = x + (size_t)idx * 8;
    uint4 v = *(const uint4*)p;
    float f[8];
    up8(v, f);
    uint4 r;
    float o[8];
#pragma unroll
    for (int k = 0; k < 8; ++k) o[k] = f[k] * ls[cb + k] + ls[C + cb + k];
    r.x = pack2(o[0], o[1]); r.y = pack2(o[2], o[3]);
    r.z = pack2(o[4], o[5]); r.w = pack2(o[6], o[7]);
    *(uint4*)p = r;
}

// ---- final 1x1 conv 32->1, fp32 out ---------------------------------------
__global__ __launch_bounds__(256) void k_final(
    const h16* __restrict__ in, const float* __restrict__ w,
    const float* __restrict__ bias, float* __restrict__ out)
{
    int idx = blockIdx.x * 256 + threadIdx.x;
    if (idx >= 524288) return;
    const h16* p = in + (size_t)idx * 32;
    float acc = bias[0];
#pragma unroll
    for (int cg = 0; cg < 4; ++cg) {
        uint4 v = *(const uint4*)(p + cg * 8);
        float f[8];
        up8(v, f);
#pragma unroll
        for (int k = 0; k < 8; ++k) acc += f[k] * w[cg * 8 + k];
    }
    out[idx] = acc;
}

extern "C" void kernel_launch(void* const* d_in, const int* in_sizes, int n_in,
                              void* d_out, int out_size, void* d_ws, size_t ws_size,
                              hipStream_t stream)
{
    const float* x      = (const float*)d_in[0];
    const float* w      = (const float*)d_in[1];
    const float* c1_w   = (const float*)d_in[2];
    const float* c1_b   = (const float*)d_in[3];
    const float* d2_w1  = (const float*)d_in[4];
    const float* d2_b1  = (const float*)d_in[5];
    const float* d2_w2  = (const float*)d_in[6];
    const float* d2_b2  = (const float*)d_in[7];
    const float* d3_w1  = (const float*)d_in[8];
    const float* d3_b1  = (const float*)d_in[9];
    const float* d3_w2  = (const float*)d_in[10];
    const float* d3_b2  = (const float*)d_in[11];
    const float* d4_w1  = (const float*)d_in[12];
    const float* d4_b1  = (const float*)d_in[13];
    const float* d4_w2  = (const float*)d_in[14];
    const float* d4_b2  = (const float*)d_in[15];
    const float* u3_w1  = (const float*)d_in[16];
    const float* u3_b1  = (const float*)d_in[17];
    const float* u3_w2  = (const float*)d_in[18];
    const float* u3_b2  = (const float*)d_in[19];
    const float* u2_w1  = (const float*)d_in[20];
    const float* u2_b1  = (const float*)d_in[21];
    const float* u2_w2  = (const float*)d_in[22];
    const float* u2_b2  = (const float*)d_in[23];
    const float* u1_w1  = (const float*)d_in[24];
    const float* u1_b1  = (const float*)d_in[25];
    const float* u1_w2  = (const float*)d_in[26];
    const float* u1_b2  = (const float*)d_in[27];
    const float* last_w = (const float*)d_in[28];
    const float* last_b = (const float*)d_in[29];
    const float* bn1_g  = (const float*)d_in[30];
    const float* bn1_b  = (const float*)d_in[31];
    const float* bn2_g  = (const float*)d_in[32];
    const float* bn2_b  = (const float*)d_in[33];
    const float* bn3_g  = (const float*)d_in[34];
    const float* bn3_b  = (const float*)d_in[35];
    const float* bn4_g  = (const float*)d_in[36];
    const float* bn4_b  = (const float*)d_in[37];
    const float* pa     = (const float*)d_in[38];
    float* out = (float*)d_out;

    // ---- fp16 arena (identical to R3-R5, proven: 166.3 MB) ----
    h16* A0 = (h16*)d_ws;
    h16* C1 = A0;                   // c1 skip  [8,256,256,32]
    h16* C2 = A0 + 16777216;        // c2 skip  [8,128,128,128]
    h16* C3 = A0 + 33554432;        // c3 skip  [8,64,64,256]
    h16* A  = A0 + 41943040;        // t0/t1/t2/t3/u3mid/u2mid/u1mid
    h16* B  = A0 + 58720256;        // p1/p2/p3/h4/u3out/u2out/u1out
    h16* PWb= A0 + 75497472;        // packed fp16 weights
    float* SUMS = (float*)(A0 + 83126272);
    float* SC   = SUMS + 1024;
    size_t need = (size_t)83126272 * 2 + 8192;
    if (ws_size < need) return;

    h16* pw_c1   = PWb;
    h16* pw_d2w1 = PWb + 16384;
    h16* pw_d2w2 = PWb + 53248;
    h16* pw_d3w1 = PWb + 200704;
    h16* pw_d3w2 = PWb + 495616;
    h16* pw_d4w1 = PWb + 1085440;
    h16* pw_d4w2 = PWb + 2265088;
    h16* pw_u3w1 = PWb + 4624384;
    h16* pw_u3w2 = PWb + 6393856;
    h16* pw_u2w1 = PWb + 6983680;
    h16* pw_u2w2 = PWb + 7426048;
    h16* pw_u1w1 = PWb + 7573504;
    h16* pw_u1w2 = PWb + 7619584;

    dim3 blk(256);

    auto pack = [&](const float* src, h16* dst, int I, int T, int O) {
        k_pack<<<dim3((I + 63) / 64, T, O), 64, 0, stream>>>(src, dst, I, T);
    };
    pack(c1_w,  pw_c1,   32, 16, 32);
    pack(d2_w1, pw_d2w1, 32,  9, 128);
    pack(d2_w2, pw_d2w2, 128, 9, 128);
    pack(d3_w1, pw_d3w1, 128, 9, 256);
    pack(d3_w2, pw_d3w2, 256, 9, 256);
    pack(d4_w1, pw_d4w1, 256, 9, 512);
    pack(d4_w2, pw_d4w2, 512, 9, 512);
    pack(u3_w1, pw_u3w1, 768, 9, 256);
    pack(u3_w2, pw_u3w2, 256, 9, 256);
    pack(u2_w1, pw_u2w1, 384, 9, 128);
    pack(u2_w2, pw_u2w2, 128, 9, 128);
    pack(u1_w1, pw_u1w1, 160, 9, 32);
    pack(u1_w2, pw_u1w2, 32,  9, 32);

    auto bn = [&](h16* buf, int C, int N, const float* g, const float* bb) {
        hipMemsetAsync(SUMS, 0, 2 * C * sizeof(float), stream);
        k_bnstats<<<dim3(1024), blk, 0, stream>>>(buf, C, N, SUMS);
        k_bnfin<<<dim3(1), dim3(512), 0, stream>>>(SUMS, g, bb, C, (float)C / (float)N, SC);
        k_bnapply<<<dim3(N / 8 / 256), blk, 0, stream>>>(buf, C, N / 8, SC);
    };

    // ---- encoder ----
    k_dynconv<<<dim3(255, 8), blk, 0, stream>>>(x, w, pa, A);   // t0 -> A
    k_conv_mfma<4,4,2,false,2><<<dim3(8, 32, 8), blk, 0, stream>>>(
        A, 32, 255, 255, nullptr, 0, 255, 255, 256, 256,
        pw_c1, c1_b, pa, 1, C1, 32);
    bn(C1, 32, 16777216, bn1_g, bn1_b);
    k_pool<<<dim3(256, 8), blk, 0, stream>>>(C1, B, 256, 256, 32, 2, 7, 65536);   // p1

    k_conv_mfma<3,3,1,false,4><<<dim3(4, 16, 16), blk, 0, stream>>>(
        B, 32, 128, 128, nullptr, 0, 128, 128, 128, 128,
        pw_d2w1, d2_b1, pa, 2, A, 128);                                            // t1
    k_conv_mfma<3,3,1,false,4><<<dim3(4, 16, 16), blk, 0, stream>>>(
        A, 128, 128, 128, nullptr, 0, 128, 128, 128, 128,
        pw_d2w2, d2_b2, pa, 3, C2, 128);
    bn(C2, 128, 16777216, bn2_g, bn2_b);
    k_pool<<<dim3(256, 8), blk, 0, stream>>>(C2, B, 128, 128, 128, 4, 6, 65536);  // p2

    k_conv_mfma<3,3,1,false,4><<<dim3(2, 8, 32), blk, 0, stream>>>(
        B, 128, 64, 64, nullptr, 0, 64, 64, 64, 64,
        pw_d3w1, d3_b1, pa, 4, A, 256);                                            // t2
    k_conv_mfma<3,3,1,false,4><<<dim3(2, 8, 32), blk, 0, stream>>>(
        A, 256, 64, 64, nullptr, 0, 64, 64, 64, 64,
        pw_d3w2, d3_b2, pa, 5, C3, 256);
    bn(C3, 256, 8388608, bn3_g, bn3_b);
    k_pool<<<dim3(128, 8), blk, 0, stream>>>(C3, B, 64, 64, 256, 5, 5, 32768);    // p3

    k_conv_mfma<3,3,1,false,4><<<dim3(1, 4, 64), blk, 0, stream>>>(
        B, 256, 32, 32, nullptr, 0, 32, 32, 32, 32,
        pw_d4w1, d4_b1, pa, 6, A, 512);                                            // t3
    k_conv_mfma<3,3,1,false,4><<<dim3(1, 4, 64), blk, 0, stream>>>(
        A, 512, 32, 32, nullptr, 0, 32, 32, 32, 32,
        pw_d4w2, d4_b2, pa, 7, B, 512);                                            // h4
    bn(B, 512, 4194304, bn4_g, bn4_b);

    // ---- decoder (bilinear up2 fused into staging) ----
    k_conv_mfma<3,3,1,true,4><<<dim3(2, 8, 32), blk, 0, stream>>>(
        B, 512, 32, 32, C3, 256, 64, 64, 64, 64,
        pw_u3w1, u3_b1, pa, 8, A, 256);                                            // u3mid
    k_conv_mfma<3,3,1,false,4><<<dim3(2, 8, 32), blk, 0, stream>>>(
        A, 256, 64, 64, nullptr, 0, 64, 64, 64, 64,
        pw_u3w2, u3_b2, pa, 9, B, 256);                                            // u3out

    k_conv_mfma<3,3,1,true,4><<<dim3(4, 16, 16), blk, 0, stream>>>(
        B, 256, 64, 64, C2, 128, 128, 128, 128, 128,
        pw_u2w1, u2_b1, pa, 10, A, 128);                                           // u2mid
    k_conv_mfma<3,3,1,false,4><<<dim3(4, 16, 16), blk, 0, stream>>>(
        A, 128, 128, 128, nullptr, 0, 128, 128, 128, 128,
        pw_u2w2, u2_b2, pa, 11, B, 128);                                           // u2out

    k_conv_mfma<3,3,1,true,2><<<dim3(8, 32, 8), blk, 0, stream>>>(
        B, 128, 128, 128, C1, 32, 256, 256, 256, 256,
        pw_u1w1, u1_b1, pa, 12, A, 32);                                            // u1mid
    k_conv_mfma<3,3,1,false,2><<<dim3(8, 32, 8), blk, 0, stream>>>(
        A, 32, 256, 256, nullptr, 0, 256, 256, 256, 256,
        pw_u1w2, u1_b2, pa, 13, B, 32);                                            // u1out

    k_final<<<dim3(2048), blk, 0, stream>>>(B, last_w, last_b, out);
}

// Round 7
// 1255.309 us; speedup vs baseline: 1.6955x; 1.6955x over previous
//
#include <hip/hip_runtime.h>
#include <hip/hip_bf16.h>
#include <cstddef>

// ---------------------------------------------------------------------------
// UNet_config1 forward — MFMA implicit-GEMM, NHWC, fp16 storage / fp32 accum.
// R7 = R5 structure (dbuf, MT=4/2, launch_bounds(256,2), persistent staging
// arrays) + swizzled weight layout [ob][tap][chunk][mt][lane][8] so A-frag
// loads are lane-coalesced (1 KB/instr) instead of 16-line scatters.
// ---------------------------------------------------------------------------

typedef _Float16 h16;
typedef __attribute__((ext_vector_type(8))) _Float16 h16x8;
typedef __attribute__((ext_vector_type(4))) float f32x4;
union F8 { uint4 u; h16x8 h; };
union UH { unsigned u; h16 h[2]; };

__device__ __forceinline__ float h2f(unsigned short s) {
    union { h16 h; unsigned short s; } c; c.s = s; return (float)c.h;
}
__device__ __forceinline__ unsigned short f2h(float f) {
    union { h16 h; unsigned short s; } c; c.h = (h16)f; return c.s;
}
__device__ __forceinline__ unsigned pack2(float a, float b) {
    return (unsigned)f2h(a) | ((unsigned)f2h(b) << 16);
}
__device__ __forceinline__ void up8(const uint4& v, float* f) {
    f[0]=h2f(v.x&0xffff); f[1]=h2f(v.x>>16);
    f[2]=h2f(v.y&0xffff); f[3]=h2f(v.y>>16);
    f[4]=h2f(v.z&0xffff); f[5]=h2f(v.z>>16);
    f[6]=h2f(v.w&0xffff); f[7]=h2f(v.w>>16);
}

// ---- weight pack: fp32 [O][I][KH][KW] -> swizzled fp16 --------------------
// dst group index: (((ob*T + t)*nch + chunk)*(OB/16) + mt)*64 + lane, 8 h16
// each; ob = o/OB, mt = (o%OB)>>4, m16 = o&15, lane = quad*16+m16,
// chunk = i/32, quad = (i>>3)&3. A-frag load becomes base + lane*16B.
__global__ void k_pack(const float* __restrict__ w, h16* __restrict__ pw,
                       int I, int T, int OB)
{
    int i8 = blockIdx.x * 64 + threadIdx.x;
    if (i8 >= (I >> 3)) return;
    int t = blockIdx.y, o = blockIdx.z;
    int ob = o / OB, om = o - ob * OB;
    int mt = om >> 4, m16 = om & 15;
    int chunk = i8 >> 2, quad = i8 & 3;
    int lane = quad * 16 + m16;
    int nch = I >> 5;
    size_t grp = ((((size_t)ob * T + t) * nch + chunk) * (OB >> 4) + mt) * 64 + lane;
    const float* src = w + ((size_t)o * I + i8 * 8) * T + t;
    h16* d = pw + grp * 8;
#pragma unroll
    for (int j = 0; j < 8; ++j) d[j] = (h16)src[(size_t)j * T];
}

// ---- implicit-GEMM conv: (16*MT) Cout x 256 px tile, 4 waves --------------
template<int KH, int KW, int PAD, bool UPS, int MT>
__global__ __launch_bounds__(256, 2) void k_conv_mfma(
    const h16* __restrict__ src1, int C1n, int H1, int W1,
    const h16* __restrict__ src2, int C2n,
    int Hin, int Win, int Ho, int Wo,
    const h16* __restrict__ PW, const float* __restrict__ bias,
    const float* __restrict__ pa, int aidx,
    h16* __restrict__ out, int Cout)
{
    constexpr int WINH = 8 + KH - 1, WINW = 32 + KW - 1;
    constexpr int NPIX = WINH * WINW;
    constexpr int NIT  = NPIX * 4;
    constexpr int MAXIT = (NIT + 255) / 256;
    constexpr int TAPS = KH * KW;
    __shared__ unsigned short lds[2][NPIX * 36];

    const int tid = threadIdx.x;
    const int lane = tid & 63, wv = tid >> 6;
    const int quad = lane >> 4, m16 = lane & 15;
    const int nCb = Cout / (16 * MT);
    const int b  = blockIdx.z / nCb, cb = blockIdx.z % nCb;
    const int x0 = blockIdx.x * 32, y0 = blockIdx.y * 8;
    const int Cin = C1n + C2n;
    const int nch = Cin >> 5;
    const int co_base = cb * (16 * MT);
    const int srcH = UPS ? Hin : H1;
    const int srcW = UPS ? Win : W1;

    // ---- chunk-invariant staging precompute (registers) ----
    int lof[MAXIT];
    int g1[MAXIT];
    int fl[MAXIT];
    unsigned fyfx[MAXIT];
    int g2[MAXIT];

    const float ry = UPS ? (float)(H1 - 1) / (float)(Hin - 1) : 0.f;
    const float rx = UPS ? (float)(W1 - 1) / (float)(Win - 1) : 0.f;
    const int W1C = UPS ? W1 * C1n : 0;

#pragma unroll
    for (int it = 0; it < MAXIT; ++it) {
        int i = tid + it * 256;
        if (i >= NIT) { lof[it] = -1; g1[it] = -1; g2[it] = -1; fl[it] = 0; fyfx[it] = 0; continue; }
        int p = i >> 2, q = i & 3;
        int wy = p / WINW, wx = p - wy * WINW;
        int yy = y0 - PAD + wy, xx = x0 - PAD + wx;
        lof[it] = p * 36 + q * 8;
        bool val = (unsigned)yy < (unsigned)srcH && (unsigned)xx < (unsigned)srcW;
        if (UPS) {
            fl[it] = 0; fyfx[it] = 0; g1[it] = -1; g2[it] = -1;
            if (val) {
                float ys = yy * ry, xs = xx * rx;
                int yl0 = (int)ys, xl0 = (int)xs;
                float fy = ys - (float)yl0, fx = xs - (float)xl0;
                g1[it] = ((b * H1 + yl0) * W1 + xl0) * C1n + q * 8;
                fl[it] = (yl0 < H1 - 1 ? 1 : 0) | (xl0 < W1 - 1 ? 2 : 0);
                fyfx[it] = pack2(fy, fx);
                g2[it] = ((b * Hin + yy) * Win + xx) * C2n + q * 8;
            }
        } else {
            fl[it] = 0; fyfx[it] = 0; g2[it] = -1;
            g1[it] = val ? ((b * H1 + yy) * W1 + xx) * C1n + q * 8 : -1;
        }
    }

    // ---- accumulators ----
    f32x4 acc[MT][4];
#pragma unroll
    for (int i = 0; i < MT; ++i)
#pragma unroll
        for (int j = 0; j < 4; ++j) acc[i][j] = (f32x4){0.f, 0.f, 0.f, 0.f};

    // ---- staging into a given LDS buffer ----
    auto stage = [&](int c0, unsigned short* buf) {
        if (UPS && c0 < C1n) {
#pragma unroll
            for (int it = 0; it < MAXIT; ++it) {
                int lo = lof[it];
                if (lo < 0) continue;
                uint2 lo8 = {0u, 0u}, hi8 = {0u, 0u};
                int g = g1[it];
                if (g >= 0) {
                    const h16* p00 = src1 + g + c0;
                    int oy = (fl[it] & 1) ? W1C : 0;
                    int ox = (fl[it] & 2) ? C1n : 0;
                    F8 v00, v01, v10, v11;
                    v00.u = *(const uint4*)(p00);
                    v01.u = *(const uint4*)(p00 + ox);
                    v10.u = *(const uint4*)(p00 + oy);
                    v11.u = *(const uint4*)(p00 + oy + ox);
                    UH t; t.u = fyfx[it];
                    h16 fy = t.h[0], fx = t.h[1];
                    h16x8 r0 = v00.h + (v10.h - v00.h) * fy;
                    h16x8 r1 = v01.h + (v11.h - v01.h) * fy;
                    F8 rr; rr.h = r0 + (r1 - r0) * fx;
                    lo8 = make_uint2(rr.u.x, rr.u.y);
                    hi8 = make_uint2(rr.u.z, rr.u.w);
                }
                *(uint2*)&buf[lo] = lo8;
                *(uint2*)&buf[lo + 4] = hi8;
            }
        } else if (UPS) {
            int cs = c0 - C1n;
#pragma unroll
            for (int it = 0; it < MAXIT; ++it) {
                int lo = lof[it];
                if (lo < 0) continue;
                uint4 v = {0u, 0u, 0u, 0u};
                int g = g2[it];
                if (g >= 0) v = *(const uint4*)(src2 + g + cs);
                *(uint2*)&buf[lo] = make_uint2(v.x, v.y);
                *(uint2*)&buf[lo + 4] = make_uint2(v.z, v.w);
            }
        } else {
#pragma unroll
            for (int it = 0; it < MAXIT; ++it) {
                int lo = lof[it];
                if (lo < 0) continue;
                uint4 v = {0u, 0u, 0u, 0u};
                int g = g1[it];
                if (g >= 0) v = *(const uint4*)(src1 + g + c0);
                *(uint2*)&buf[lo] = make_uint2(v.x, v.y);
                *(uint2*)&buf[lo + 4] = make_uint2(v.z, v.w);
            }
        }
    };

    // ---- MFMA sweep; A-frags via coalesced swizzled loads ----
    const uint4* PW4 = (const uint4*)PW;
    auto sweep = [&](int ci, const unsigned short* buf) {
        size_t abase = (((size_t)cb * TAPS) * nch + ci) * (MT * 64) + lane;
        const size_t astep = (size_t)nch * (MT * 64);
#pragma unroll
        for (int ky = 0; ky < KH; ++ky) {
#pragma unroll
            for (int kx = 0; kx < KW; ++kx) {
                const int tap = ky * KW + kx;
                F8 a[MT];
#pragma unroll
                for (int mt = 0; mt < MT; ++mt)
                    a[mt].u = PW4[abase + (size_t)tap * astep + mt * 64];
#pragma unroll
                for (int nt = 0; nt < 4; ++nt) {
                    int rowl = (wv << 1) + (nt >> 1);
                    int col  = ((nt & 1) << 4) + m16;
                    int li = ((rowl + ky) * WINW + col + kx) * 36 + quad * 8;
                    F8 bf;
                    ((uint2*)&bf)[0] = *(const uint2*)&buf[li];
                    ((uint2*)&bf)[1] = *(const uint2*)&buf[li + 4];
#pragma unroll
                    for (int mt = 0; mt < MT; ++mt)
                        acc[mt][nt] = __builtin_amdgcn_mfma_f32_16x16x32_f16(
                            a[mt].h, bf.h, acc[mt][nt], 0, 0, 0);
                }
            }
        }
    };

    // ---- double-buffered K-loop: one barrier per chunk ----
    stage(0, lds[0]);
    __syncthreads();
    for (int ci = 0; ci < nch; ++ci) {
        int p = ci & 1;
        if (ci + 1 < nch) stage((ci + 1) << 5, lds[p ^ 1]);
        sweep(ci, lds[p]);
        __syncthreads();
    }

    // ---- epilogue: bias + PReLU, NHWC store ----
    const float alpha = pa[aidx];
#pragma unroll
    for (int mt = 0; mt < MT; ++mt) {
        int co = co_base + mt * 16 + quad * 4;
        float4 bi = *(const float4*)(bias + co);
#pragma unroll
        for (int nt = 0; nt < 4; ++nt) {
            int y = y0 + (wv << 1) + (nt >> 1);
            int x = x0 + ((nt & 1) << 4) + m16;
            float v0 = acc[mt][nt][0] + bi.x;
            float v1 = acc[mt][nt][1] + bi.y;
            float v2 = acc[mt][nt][2] + bi.z;
            float v3 = acc[mt][nt][3] + bi.w;
            v0 = v0 >= 0.f ? v0 : alpha * v0;
            v1 = v1 >= 0.f ? v1 : alpha * v1;
            v2 = v2 >= 0.f ? v2 : alpha * v2;
            v3 = v3 >= 0.f ? v3 : alpha * v3;
            uint2 r; r.x = pack2(v0, v1); r.y = pack2(v2, v3);
            *(uint2*)(out + ((size_t)((b * Ho + y) * Wo + x)) * Cout + co) = r;
        }
    }
}

// ---- dynamic per-sample conv 8x8 pad3 + PReLU[0], NHWC out ----------------
__global__ __launch_bounds__(256) void k_dynconv(
    const float* __restrict__ x,   // [8,256,256] fp32
    const float* __restrict__ w,   // [8,32,8,8] fp32
    const float* __restrict__ pa,
    h16* __restrict__ out)         // [8,255,255,32] NHWC
{
    __shared__ float wl[2048];     // [tap][co]
    int b = blockIdx.y;
    for (int j = threadIdx.x; j < 2048; j += 256) {
        int t = j >> 5, co = j & 31;
        wl[j] = w[((size_t)(b * 32 + co)) * 64 + t];
    }
    __syncthreads();
    int idx = blockIdx.x * 256 + threadIdx.x;
    if (idx >= 65025) return;
    int py = idx / 255, px = idx - py * 255;
    float acc[32];
#pragma unroll
    for (int c = 0; c < 32; ++c) acc[c] = 0.f;
    const float* xp = x + (size_t)b * 65536;
#pragma unroll
    for (int ky = 0; ky < 8; ++ky) {
        int iy = py + ky - 3;
        if ((unsigned)iy >= 256u) continue;
        const float* row = xp + iy * 256;
#pragma unroll
        for (int kx = 0; kx < 8; ++kx) {
            int ix = px + kx - 3;
            if ((unsigned)ix >= 256u) continue;
            float v = row[ix];
            const float4* wr = (const float4*)&wl[(ky * 8 + kx) * 32];
#pragma unroll
            for (int cg = 0; cg < 8; ++cg) {
                float4 wv = wr[cg];
                acc[cg*4+0] += v * wv.x; acc[cg*4+1] += v * wv.y;
                acc[cg*4+2] += v * wv.z; acc[cg*4+3] += v * wv.w;
            }
        }
    }
    float a = pa[0];
    h16* op = out + ((size_t)(b * 65025 + idx)) * 32;
#pragma unroll
    for (int cg = 0; cg < 4; ++cg) {
        float v[8];
#pragma unroll
        for (int k = 0; k < 8; ++k) {
            float t = acc[cg * 8 + k];
            v[k] = t >= 0.f ? t : a * t;
        }
        uint4 r;
        r.x = pack2(v[0], v[1]); r.y = pack2(v[2], v[3]);
        r.z = pack2(v[4], v[5]); r.w = pack2(v[6], v[7]);
        *(uint4*)(op + cg * 8) = r;
    }
}

// ---- maxpool 2x2, NHWC, vector 8ch ----------------------------------------
__global__ __launch_bounds__(256) void k_pool(
    const h16* __restrict__ in, h16* __restrict__ out,
    int Hin, int Win, int C, int lc8, int lwo, int count)
{
    int idx = blockIdx.x * 256 + threadIdx.x;
    if (idx >= count) return;
    int b = blockIdx.y;
    int c8 = idx & ((1 << lc8) - 1);
    int t  = idx >> lc8;
    int ox = t & ((1 << lwo) - 1);
    int oy = t >> lwo;
    const h16* p = in + ((size_t)((b * Hin + oy * 2) * Win + ox * 2)) * C + c8 * 8;
    uint4 v00 = *(const uint4*)p;
    uint4 v01 = *(const uint4*)(p + C);
    uint4 v10 = *(const uint4*)(p + (size_t)Win * C);
    uint4 v11 = *(const uint4*)(p + (size_t)Win * C + C);
    float a[8], bb[8], c[8], d[8];
    up8(v00, a); up8(v01, bb); up8(v10, c); up8(v11, d);
    uint4 r;
    float m[8];
#pragma unroll
    for (int k = 0; k < 8; ++k) m[k] = fmaxf(fmaxf(a[k], bb[k]), fmaxf(c[k], d[k]));
    r.x = pack2(m[0], m[1]); r.y = pack2(m[2], m[3]);
    r.z = pack2(m[4], m[5]); r.w = pack2(m[6], m[7]);
    int Wo = 1 << lwo;
    *(uint4*)(out + ((size_t)((b * (Hin >> 1) + oy) * Wo + ox)) * C + c8 * 8) = r;
}

// ---- BatchNorm (training stats), NHWC -------------------------------------
__global__ __launch_bounds__(256) void k_bnstats(
    const h16* __restrict__ x, int C, int N, float* __restrict__ sums)
{
    __shared__ float ls[1024];
    for (int j = threadIdx.x; j < 2 * C; j += 256) ls[j] = 0.f;
    __syncthreads();
    int start = blockIdx.x * 256 + threadIdx.x;
    int stride = gridDim.x * 256;
    int c = start & (C - 1);
    float s = 0.f, q = 0.f;
    for (int i = start; i < N; i += stride) {
        float v = h2f(((const unsigned short*)x)[i]);
        s += v; q += v * v;
    }
    atomicAdd(&ls[c], s);
    atomicAdd(&ls[C + c], q);
    __syncthreads();
    for (int j = threadIdx.x; j < 2 * C; j += 256) atomicAdd(&sums[j], ls[j]);
}

__global__ void k_bnfin(
    const float* __restrict__ sums, const float* __restrict__ g,
    const float* __restrict__ bta, int C, float invN, float* __restrict__ sc)
{
    int c = threadIdx.x;
    if (c >= C) return;
    float mean = sums[c] * invN;
    float var  = sums[C + c] * invN - mean * mean;
    float s    = g[c] / sqrtf(var + 1e-5f);
    sc[c]      = s;
    sc[C + c]  = bta[c] - mean * s;
}

__global__ __launch_bounds__(256) void k_bnapply(
    h16* __restrict__ x, int C, int N8, const float* __restrict__ sc)
{
    __shared__ float ls[1024];
    for (int j = threadIdx.x; j < 2 * C; j += 256) ls[j] = sc[j];
    __syncthreads();
    int idx = blockIdx.x * 256 + threadIdx.x;
    if (idx >= N8) return;
    int cb = (idx << 3) & (C - 1);
    h16* p = x + (size_t)idx * 8;
    uint4 v = *(const uint4*)p;
    float f[8];
    up8(v, f);
    uint4 r;
    float o[8];
#pragma unroll
    for (int k = 0; k < 8; ++k) o[k] = f[k] * ls[cb + k] + ls[C + cb + k];
    r.x = pack2(o[0], o[1]); r.y = pack2(o[2], o[3]);
    r.z = pack2(o[4], o[5]); r.w = pack2(o[6], o[7]);
    *(uint4*)p = r;
}

// ---- final 1x1 conv 32->1, fp32 out ---------------------------------------
__global__ __launch_bounds__(256) void k_final(
    const h16* __restrict__ in, const float* __restrict__ w,
    const float* __restrict__ bias, float* __restrict__ out)
{
    int idx = blockIdx.x * 256 + threadIdx.x;
    if (idx >= 524288) return;
    const h16* p = in + (size_t)idx * 32;
    float acc = bias[0];
#pragma unroll
    for (int cg = 0; cg < 4; ++cg) {
        uint4 v = *(const uint4*)(p + cg * 8);
        float f[8];
        up8(v, f);
#pragma unroll
        for (int k = 0; k < 8; ++k) acc += f[k] * w[cg * 8 + k];
    }
    out[idx] = acc;
}

extern "C" void kernel_launch(void* const* d_in, const int* in_sizes, int n_in,
                              void* d_out, int out_size, void* d_ws, size_t ws_size,
                              hipStream_t stream)
{
    const float* x      = (const float*)d_in[0];
    const float* w      = (const float*)d_in[1];
    const float* c1_w   = (const float*)d_in[2];
    const float* c1_b   = (const float*)d_in[3];
    const float* d2_w1  = (const float*)d_in[4];
    const float* d2_b1  = (const float*)d_in[5];
    const float* d2_w2  = (const float*)d_in[6];
    const float* d2_b2  = (const float*)d_in[7];
    const float* d3_w1  = (const float*)d_in[8];
    const float* d3_b1  = (const float*)d_in[9];
    const float* d3_w2  = (const float*)d_in[10];
    const float* d3_b2  = (const float*)d_in[11];
    const float* d4_w1  = (const float*)d_in[12];
    const float* d4_b1  = (const float*)d_in[13];
    const float* d4_w2  = (const float*)d_in[14];
    const float* d4_b2  = (const float*)d_in[15];
    const float* u3_w1  = (const float*)d_in[16];
    const float* u3_b1  = (const float*)d_in[17];
    const float* u3_w2  = (const float*)d_in[18];
    const float* u3_b2  = (const float*)d_in[19];
    const float* u2_w1  = (const float*)d_in[20];
    const float* u2_b1  = (const float*)d_in[21];
    const float* u2_w2  = (const float*)d_in[22];
    const float* u2_b2  = (const float*)d_in[23];
    const float* u1_w1  = (const float*)d_in[24];
    const float* u1_b1  = (const float*)d_in[25];
    const float* u1_w2  = (const float*)d_in[26];
    const float* u1_b2  = (const float*)d_in[27];
    const float* last_w = (const float*)d_in[28];
    const float* last_b = (const float*)d_in[29];
    const float* bn1_g  = (const float*)d_in[30];
    const float* bn1_b  = (const float*)d_in[31];
    const float* bn2_g  = (const float*)d_in[32];
    const float* bn2_b  = (const float*)d_in[33];
    const float* bn3_g  = (const float*)d_in[34];
    const float* bn3_b  = (const float*)d_in[35];
    const float* bn4_g  = (const float*)d_in[36];
    const float* bn4_b  = (const float*)d_in[37];
    const float* pa     = (const float*)d_in[38];
    float* out = (float*)d_out;

    // ---- fp16 arena (identical to R3-R5, proven: 166.3 MB) ----
    h16* A0 = (h16*)d_ws;
    h16* C1 = A0;                   // c1 skip  [8,256,256,32]
    h16* C2 = A0 + 16777216;        // c2 skip  [8,128,128,128]
    h16* C3 = A0 + 33554432;        // c3 skip  [8,64,64,256]
    h16* A  = A0 + 41943040;        // t0/t1/t2/t3/u3mid/u2mid/u1mid
    h16* B  = A0 + 58720256;        // p1/p2/p3/h4/u3out/u2out/u1out
    h16* PWb= A0 + 75497472;        // packed fp16 weights (swizzled)
    float* SUMS = (float*)(A0 + 83126272);
    float* SC   = SUMS + 1024;
    size_t need = (size_t)83126272 * 2 + 8192;
    if (ws_size < need) return;

    h16* pw_c1   = PWb;
    h16* pw_d2w1 = PWb + 16384;
    h16* pw_d2w2 = PWb + 53248;
    h16* pw_d3w1 = PWb + 200704;
    h16* pw_d3w2 = PWb + 495616;
    h16* pw_d4w1 = PWb + 1085440;
    h16* pw_d4w2 = PWb + 2265088;
    h16* pw_u3w1 = PWb + 4624384;
    h16* pw_u3w2 = PWb + 6393856;
    h16* pw_u2w1 = PWb + 6983680;
    h16* pw_u2w2 = PWb + 7426048;
    h16* pw_u1w1 = PWb + 7573504;
    h16* pw_u1w2 = PWb + 7619584;

    dim3 blk(256);

    // pack with swizzle; OB = 16*MT of the consuming conv kernel
    auto pack = [&](const float* src, h16* dst, int I, int T, int O, int OB) {
        k_pack<<<dim3(((I >> 3) + 63) / 64, T, O), 64, 0, stream>>>(src, dst, I, T, OB);
    };
    pack(c1_w,  pw_c1,   32, 16, 32, 32);
    pack(d2_w1, pw_d2w1, 32,  9, 128, 64);
    pack(d2_w2, pw_d2w2, 128, 9, 128, 64);
    pack(d3_w1, pw_d3w1, 128, 9, 256, 64);
    pack(d3_w2, pw_d3w2, 256, 9, 256, 64);
    pack(d4_w1, pw_d4w1, 256, 9, 512, 64);
    pack(d4_w2, pw_d4w2, 512, 9, 512, 64);
    pack(u3_w1, pw_u3w1, 768, 9, 256, 64);
    pack(u3_w2, pw_u3w2, 256, 9, 256, 64);
    pack(u2_w1, pw_u2w1, 384, 9, 128, 64);
    pack(u2_w2, pw_u2w2, 128, 9, 128, 64);
    pack(u1_w1, pw_u1w1, 160, 9, 32, 32);
    pack(u1_w2, pw_u1w2, 32,  9, 32, 32);

    auto bn = [&](h16* buf, int C, int N, const float* g, const float* bb) {
        hipMemsetAsync(SUMS, 0, 2 * C * sizeof(float), stream);
        k_bnstats<<<dim3(1024), blk, 0, stream>>>(buf, C, N, SUMS);
        k_bnfin<<<dim3(1), dim3(512), 0, stream>>>(SUMS, g, bb, C, (float)C / (float)N, SC);
        k_bnapply<<<dim3(N / 8 / 256), blk, 0, stream>>>(buf, C, N / 8, SC);
    };

    // ---- encoder ----
    k_dynconv<<<dim3(255, 8), blk, 0, stream>>>(x, w, pa, A);   // t0 -> A
    k_conv_mfma<4,4,2,false,2><<<dim3(8, 32, 8), blk, 0, stream>>>(
        A, 32, 255, 255, nullptr, 0, 255, 255, 256, 256,
        pw_c1, c1_b, pa, 1, C1, 32);
    bn(C1, 32, 16777216, bn1_g, bn1_b);
    k_pool<<<dim3(256, 8), blk, 0, stream>>>(C1, B, 256, 256, 32, 2, 7, 65536);   // p1

    k_conv_mfma<3,3,1,false,4><<<dim3(4, 16, 16), blk, 0, stream>>>(
        B, 32, 128, 128, nullptr, 0, 128, 128, 128, 128,
        pw_d2w1, d2_b1, pa, 2, A, 128);                                            // t1
    k_conv_mfma<3,3,1,false,4><<<dim3(4, 16, 16), blk, 0, stream>>>(
        A, 128, 128, 128, nullptr, 0, 128, 128, 128, 128,
        pw_d2w2, d2_b2, pa, 3, C2, 128);
    bn(C2, 128, 16777216, bn2_g, bn2_b);
    k_pool<<<dim3(256, 8), blk, 0, stream>>>(C2, B, 128, 128, 128, 4, 6, 65536);  // p2

    k_conv_mfma<3,3,1,false,4><<<dim3(2, 8, 32), blk, 0, stream>>>(
        B, 128, 64, 64, nullptr, 0, 64, 64, 64, 64,
        pw_d3w1, d3_b1, pa, 4, A, 256);                                            // t2
    k_conv_mfma<3,3,1,false,4><<<dim3(2, 8, 32), blk, 0, stream>>>(
        A, 256, 64, 64, nullptr, 0, 64, 64, 64, 64,
        pw_d3w2, d3_b2, pa, 5, C3, 256);
    bn(C3, 256, 8388608, bn3_g, bn3_b);
    k_pool<<<dim3(128, 8), blk, 0, stream>>>(C3, B, 64, 64, 256, 5, 5, 32768);    // p3

    k_conv_mfma<3,3,1,false,4><<<dim3(1, 4, 64), blk, 0, stream>>>(
        B, 256, 32, 32, nullptr, 0, 32, 32, 32, 32,
        pw_d4w1, d4_b1, pa, 6, A, 512);                                            // t3
    k_conv_mfma<3,3,1,false,4><<<dim3(1, 4, 64), blk, 0, stream>>>(
        A, 512, 32, 32, nullptr, 0, 32, 32, 32, 32,
        pw_d4w2, d4_b2, pa, 7, B, 512);                                            // h4
    bn(B, 512, 4194304, bn4_g, bn4_b);

    // ---- decoder (bilinear up2 fused into staging) ----
    k_conv_mfma<3,3,1,true,4><<<dim3(2, 8, 32), blk, 0, stream>>>(
        B, 512, 32, 32, C3, 256, 64, 64, 64, 64,
        pw_u3w1, u3_b1, pa, 8, A, 256);                                            // u3mid
    k_conv_mfma<3,3,1,false,4><<<dim3(2, 8, 32), blk, 0, stream>>>(
        A, 256, 64, 64, nullptr, 0, 64, 64, 64, 64,
        pw_u3w2, u3_b2, pa, 9, B, 256);                                            // u3out

    k_conv_mfma<3,3,1,true,4><<<dim3(4, 16, 16), blk, 0, stream>>>(
        B, 256, 64, 64, C2, 128, 128, 128, 128, 128,
        pw_u2w1, u2_b1, pa, 10, A, 128);                                           // u2mid
    k_conv_mfma<3,3,1,false,4><<<dim3(4, 16, 16), blk, 0, stream>>>(
        A, 128, 128, 128, nullptr, 0, 128, 128, 128, 128,
        pw_u2w2, u2_b2, pa, 11, B, 128);                                           // u2out

    k_conv_mfma<3,3,1,true,2><<<dim3(8, 32, 8), blk, 0, stream>>>(
        B, 128, 128, 128, C1, 32, 256, 256, 256, 256,
        pw_u1w1, u1_b1, pa, 12, A, 32);                                            // u1mid
    k_conv_mfma<3,3,1,false,2><<<dim3(8, 32, 8), blk, 0, stream>>>(
        A, 32, 256, 256, nullptr, 0, 256, 256, 256, 256,
        pw_u1w2, u1_b2, pa, 13, B, 32);                                            // u1out

    k_final<<<dim3(2048), blk, 0, stream>>>(B, last_w, last_b, out);
}